// Round 9
// baseline (79.707 us; speedup 1.0000x reference)
//
#include <hip/hip_runtime.h>
#include <math.h>

#define T_DIM 512
#define B_DIM 64
#define D_DIM 256
#define F_DIM 256
#define ALPHA 0.2f
#define L2E 1.44269504089f
#define NEGL -1.0e38f

// workspace layout (floats). Every slot consumed is zeroed/written the same call.
#define P_OFF 0
#define Q_OFF (P_OFF + B_DIM * T_DIM)
#define M_OFF (Q_OFF + B_DIM * T_DIM)              // [3][B]  f2-max (log2 domain)
#define R_OFF (M_OFF + 3 * B_DIM)                  // [3][B][T] row sums (atomic)

__device__ __forceinline__ float dot4(float4 a, float4 b) {
    return a.x * b.x + a.y * b.y + a.z * b.z + a.w * b.w;
}

// ---------- Node 1: per-b front end. 64 blocks x 1024 threads ----------
// redundant u,v per block -> p,q for this b -> M[w] -> zero R slices + out[b].
__global__ __launch_bounds__(1024) void g_front(const float* __restrict__ x,
                                                const int* __restrict__ turns,
                                                const float* __restrict__ W,
                                                const float* __restrict__ a1,
                                                const float* __restrict__ a2,
                                                float* __restrict__ ws,
                                                float* __restrict__ out) {
    int b = blockIdx.x, tid = threadIdx.x;
    int wave = tid >> 6, lane = tid & 63;
    __shared__ float a1s[F_DIM], a2s[F_DIM];
    __shared__ float su[D_DIM], sv[D_DIM];
    __shared__ float sp[T_DIM], sq[T_DIM];
    __shared__ float red[3][8];

    if (tid < 256) out[b * F_DIM + tid] = 0.f;
    for (int k = tid; k < 3 * T_DIM; k += 1024)
        ws[R_OFF + ((k >> 9) * B_DIM + b) * T_DIM + (k & 511)] = 0.f;
    if (tid < 64) ((float4*)a1s)[tid] = ((const float4*)a1)[tid];
    else if (tid < 128) ((float4*)a2s)[tid - 64] = ((const float4*)a2)[tid - 64];
    __syncthreads();

    // u,v: wave handles d = wave + 16*i; one coalesced W-row read serves both dots
    {
        float4 A = ((const float4*)a1s)[lane];
        float4 Bv = ((const float4*)a2s)[lane];
#pragma unroll 4
        for (int i = 0; i < 16; ++i) {
            int d = wave + 16 * i;
            float4 wv = ((const float4*)(W + (size_t)d * F_DIM))[lane];
            float p = dot4(wv, A), q = dot4(wv, Bv);
            for (int off = 32; off > 0; off >>= 1) {
                p += __shfl_down(p, off);
                q += __shfl_down(q, off);
            }
            if (lane == 0) { su[d] = p; sv[d] = q; }
        }
    }
    __syncthreads();

    // p,q for this b: wave handles t = wave + 16*i (wave-uniform guard)
    int tn = turns[b];
    {
        float4 uu = ((const float4*)su)[lane];
        float4 vv = ((const float4*)sv)[lane];
#pragma unroll 4
        for (int i = 0; i < 32; ++i) {
            int t = wave + 16 * i;
            if (t <= tn) {
                float4 xv = ((const float4*)x)[((size_t)t * B_DIM + b) * (D_DIM / 4) + lane];
                float pp = dot4(xv, uu), qq = dot4(xv, vv);
                for (int off = 32; off > 0; off >>= 1) {
                    pp += __shfl_down(pp, off);
                    qq += __shfl_down(qq, off);
                }
                if (lane == 0) {
                    sp[t] = pp; sq[t] = qq;
                    ws[P_OFF + b * T_DIM + t] = pp;
                    ws[Q_OFF + b * T_DIM + t] = qq;
                }
            }
        }
    }
    __syncthreads();

    // M[w] = max_j f2L[w][j] (log2-scaled); waves 0..7 (tid<512), j = tid
    if (tid < 512) {
        int j = tid;
#pragma unroll
        for (int w = 1; w <= 3; ++w) {
            int cnt = tn - w + 2;
            if (cnt > T_DIM) cnt = T_DIM;
            float v = NEGL;
            if (j < cnt) {                  // j+w-1 <= tn: sq written
                float a = sq[j];
                if (w > 1) a += sq[j + 1];
                if (w > 2) a += sq[j + 2];
                v = a * (L2E / (float)w);
            }
            float m = v;
            for (int off = 32; off > 0; off >>= 1) m = fmaxf(m, __shfl_down(m, off));
            if (lane == 0) red[w - 1][wave] = m;
        }
    }
    __syncthreads();
    if (tid < 3) {
        float M = red[tid][0];
#pragma unroll
        for (int k = 1; k < 8; ++k) M = fmaxf(M, red[tid][k]);
        ws[M_OFF + tid * B_DIM + b] = M;
    }
}

// ---------- Node 2: balanced row pass. 768 blocks (b,w,jc) x 512 thr ----------
__global__ __launch_bounds__(512) void g_row(const int* __restrict__ turns,
                                             float* __restrict__ ws) {
    int bi = blockIdx.x, tid = threadIdx.x;
    int b = bi / 12, rem = bi % 12;
    int w = (rem >> 2) + 1, jc = rem & 3;
    int tn = turns[b];
    int cnt = tn - w + 2;
    if (cnt > T_DIM) cnt = T_DIM;
    if (cnt <= 0) return;                 // block-uniform; R stays 0
    int j0 = jc * 128;
    if (j0 >= cnt) return;                // block-uniform
    __shared__ float sp[T_DIM], f2L[128];
    if (tid < 128) ((float4*)sp)[tid] = ((const float4*)(ws + P_OFF + b * T_DIM))[tid];
    if (tid < 128) {
        int j = j0 + tid;
        float v = NEGL;
        if (j < cnt) {
            const float* Q = ws + Q_OFF + b * T_DIM;
            float a = Q[j];
            if (w > 1) a += Q[j + 1];
            if (w > 2) a += Q[j + 2];
            v = a * (L2E / (float)w);
        }
        f2L[tid] = v;
    }
    __syncthreads();
    float M = ws[M_OFF + (w - 1) * B_DIM + b];
    int i = tid;
    if (i < cnt) {
        float a = sp[i];
        if (w > 1) a += sp[i + 1];
        if (w > 2) a += sp[i + 2];
        float f1 = a * (L2E / (float)w);
        float s0 = f1 + M;
        float mrow = fmaxf(s0, ALPHA * s0);   // analytic row max (lrelu monotone)
        float r = 0.f;
        int n = min(128, cnt - j0);
        for (int k = 0; k < n; ++k) {
            float s = f1 + f2L[k];
            s = fmaxf(s, ALPHA * s);
            r += __builtin_amdgcn_exp2f(s - mrow);
        }
        atomicAdd(&ws[R_OFF + ((w - 1) * B_DIM + b) * T_DIM + i], r);
    }
}

// ---------- Node 3: fused col pass + Z + GEMV. 256 blocks (b, t-chunk) x 512 ----------
__global__ __launch_bounds__(512) void g_colzout(const float* __restrict__ x,
                                                 const int* __restrict__ turns,
                                                 const float* __restrict__ W,
                                                 const float* __restrict__ ws,
                                                 float* __restrict__ out) {
    int b = blockIdx.x >> 2, chunk = blockIdx.x & 3;
    int tn = turns[b];
    int t0 = chunk * 128;
    if (t0 > tn) return;                  // C=0 there; out zero'd in Node 1
    int tid = threadIdx.x;
    __shared__ float sp[T_DIM], sq[T_DIM];
    __shared__ float fx[T_DIM], fy[T_DIM];       // f1_i, ci_i (log2 domain)
    __shared__ float Gs[3][130];                 // GG[w] on j = t0-2 .. t0+127
    __shared__ float partq[128][4];
    __shared__ float part2[2][128];
    __shared__ float Cs[128];
    __shared__ float4 zp[512];
    __shared__ float Zs[D_DIM];
    __shared__ float ored[512];

    if (tid < 128) {
        ((float4*)sp)[tid] = ((const float4*)(ws + P_OFF + b * T_DIM))[tid];
        ((float4*)sq)[tid] = ((const float4*)(ws + Q_OFF + b * T_DIM))[tid];
    }
    __syncthreads();

    for (int w = 1; w <= 3; ++w) {
        int cnt = tn - w + 2;
        if (cnt > T_DIM) cnt = T_DIM;
        bool active = cnt > 0;            // block-uniform
        float scale = L2E / (float)w;
        float Mw = active ? ws[M_OFF + (w - 1) * B_DIM + b] : 0.f;
        if (active) {
            int i = tid;
            if (i < cnt) {                // fill fc; i+w-1 <= tn in-bounds
                float a = sp[i];
                if (w > 1) a += sp[i + 1];
                if (w > 2) a += sp[i + 2];
                float f1 = a * scale;
                float s0 = f1 + Mw;
                float mrow = fmaxf(s0, ALPHA * s0);
                float ri = ws[R_OFF + ((w - 1) * B_DIM + b) * T_DIM + i];
                fx[i] = f1;
                fy[i] = mrow + __builtin_amdgcn_logf(ri);  // log2
            }
        } else if (tid < 130) {
            Gs[w - 1][tid] = 0.f;
        }
        __syncthreads();
        if (active) {
            // phase I: j = t0 + (tid>>2), i-quarter q = tid&3
            {
                int jj = tid >> 2, q = tid & 3;
                int j = t0 + jj;
                float acc = 0.f;
                if (j < cnt) {
                    float a = sq[j];
                    if (w > 1) a += sq[j + 1];
                    if (w > 2) a += sq[j + 2];
                    float f2j = a * scale;
                    int i1 = min((q + 1) * 128, cnt);
                    for (int i = q * 128; i < i1; ++i) {
                        float s = fx[i] + f2j;
                        s = fmaxf(s, ALPHA * s);
                        acc += __builtin_amdgcn_exp2f(s - fy[i]);
                    }
                }
                partq[jj][q] = acc;
            }
            // phase II: j = t0-2, t0-1 with 128-way i-split
            if (tid < 256) {
                int e = tid >> 7, q = tid & 127;
                int j = t0 - 2 + e;
                float acc = 0.f;
                if (j >= 0 && j < cnt) {
                    float a = sq[j];
                    if (w > 1) a += sq[j + 1];
                    if (w > 2) a += sq[j + 2];
                    float f2j = a * scale;
                    for (int i = q; i < cnt; i += 128) {
                        float s = fx[i] + f2j;
                        s = fmaxf(s, ALPHA * s);
                        acc += __builtin_amdgcn_exp2f(s - fy[i]);
                    }
                }
                part2[e][q] = acc;
            }
        }
        __syncthreads();
        if (active) {
            float invc = 1.0f / (float)cnt;
            if (tid < 128) {
                int j = t0 + tid;
                float s = partq[tid][0] + partq[tid][1] + partq[tid][2] + partq[tid][3];
                Gs[w - 1][2 + tid] = (j < cnt) ? s * invc : 0.f;
            } else if (tid < 130) {
                int e = tid - 128;
                int j = t0 - 2 + e;
                float s = 0.f;
                for (int k = 0; k < 128; ++k) s += part2[e][k];
                Gs[w - 1][e] = (j >= 0 && j < cnt) ? s * invc : 0.f;
            }
        }
        __syncthreads();
    }

    // C[t] with vws folded
    if (tid < 128) {
        float g1 = Gs[0][2 + tid];
        float g2 = Gs[1][2 + tid] + Gs[1][1 + tid];
        float g3 = Gs[2][2 + tid] + Gs[2][1 + tid] + Gs[2][tid];
        float vws = 1.f + (tn >= 1 ? 1.f : 0.f) + (tn >= 2 ? 1.f : 0.f);
        Cs[tid] = (g1 + 0.5f * g2 + (1.0f / 3.0f) * g3) / vws;
    }
    __syncthreads();

    // Z accumulate over this t-chunk (proven body)
    int wave = tid >> 6, lane = tid & 63;
    float4 z = make_float4(0.f, 0.f, 0.f, 0.f);
    {
        size_t base = ((size_t)(t0 + wave * 16) * B_DIM + b) * (D_DIM / 4) + lane;
#pragma unroll 8
        for (int tt = 0; tt < 16; ++tt) {
            float c = Cs[wave * 16 + tt];
            float4 xv = ((const float4*)x)[base + (size_t)tt * (B_DIM * D_DIM / 4)];
            z.x += c * xv.x; z.y += c * xv.y; z.z += c * xv.z; z.w += c * xv.w;
        }
    }
    zp[tid] = z;
    __syncthreads();
    if (tid < 64) {
        float4 a = zp[tid];
#pragma unroll
        for (int k = 1; k < 8; ++k) {
            float4 bb = zp[k * 64 + tid];
            a.x += bb.x; a.y += bb.y; a.z += bb.z; a.w += bb.w;
        }
        ((float4*)Zs)[tid] = a;
    }
    __syncthreads();
    int f = tid & 255, dh = tid >> 8;
    float acc = 0.f;
#pragma unroll 8
    for (int dd = dh * 128; dd < dh * 128 + 128; ++dd)
        acc += Zs[dd] * W[(size_t)dd * F_DIM + f];
    ored[tid] = acc;
    __syncthreads();
    if (tid < 256)
        atomicAdd(&out[b * F_DIM + tid], ored[tid] + ored[tid + 256]);
}

extern "C" void kernel_launch(void* const* d_in, const int* in_sizes, int n_in,
                              void* d_out, int out_size, void* d_ws, size_t ws_size,
                              hipStream_t stream) {
    const float* x = (const float*)d_in[0];     // (T,B,D) fp32
    const int* turns = (const int*)d_in[1];     // (B,) int32
    const float* W = (const float*)d_in[2];     // (D,F)
    const float* a1 = (const float*)d_in[3];    // (F,)
    const float* a2 = (const float*)d_in[4];    // (F,)
    float* out = (float*)d_out;                 // (B,F)
    float* ws = (float*)d_ws;

    g_front<<<B_DIM, 1024, 0, stream>>>(x, turns, W, a1, a2, ws, out);
    g_row<<<B_DIM * 12, 512, 0, stream>>>(turns, ws);
    g_colzout<<<B_DIM * 4, 512, 0, stream>>>(x, turns, W, ws, out);
}

// Round 10
// 78.359 us; speedup vs baseline: 1.0172x; 1.0172x over previous
//
#include <hip/hip_runtime.h>
#include <math.h>

#define T_DIM 512
#define B_DIM 64
#define D_DIM 256
#define F_DIM 256
#define ALPHA 0.2f
#define L2E 1.44269504089f
#define NEGL -1.0e38f

// workspace: GG[3][B][T] only
#define GG_OFF 0

__device__ __forceinline__ float dot4(float4 a, float4 b) {
    return a.x * b.x + a.y * b.y + a.z * b.z + a.w * b.w;
}

// ---------- Node 1: one block per (b,w): uv + pq (redundant) + full softmax ----------
// 192 blocks x 1024 threads. Writes GG[w-1][b][0..511]; blocks 0..31 zero d_out.
__global__ __launch_bounds__(1024, 1) void g_attn_all(const float* __restrict__ x,
                                                      const int* __restrict__ turns,
                                                      const float* __restrict__ W,
                                                      const float* __restrict__ a1,
                                                      const float* __restrict__ a2,
                                                      float* __restrict__ ws,
                                                      float* __restrict__ out) {
    int bi = blockIdx.x, tid = threadIdx.x;
    int wave = tid >> 6, lane = tid & 63;
    if (bi < 32 && tid < 512) out[bi * 512 + tid] = 0.f;  // zero d_out for Node 2
    int b = bi / 3, w = bi % 3 + 1;
    int tn = turns[b];
    int cnt = tn - w + 2;
    if (cnt > T_DIM) cnt = T_DIM;
    float* GG = ws + GG_OFF + ((w - 1) * B_DIM + b) * T_DIM;
    if (cnt <= 0) {                        // block-uniform, before any __syncthreads
        if (tid < 512) GG[tid] = 0.f;
        return;
    }

    __shared__ float a1s[F_DIM], a2s[F_DIM], su[D_DIM], sv[D_DIM];
    __shared__ float sp[T_DIM], sq[T_DIM], f2L[T_DIM], fx[T_DIM], fy[T_DIM];
    __shared__ float part[2][T_DIM];
    __shared__ float red[8];

    if (tid < 64) ((float4*)a1s)[tid] = ((const float4*)a1)[tid];
    else if (tid < 128) ((float4*)a2s)[tid - 64] = ((const float4*)a2)[tid - 64];
    __syncthreads();

    // u,v (redundant per block): wave handles d = wave + 16*i; 8-deep prefetch
    {
        float4 A = ((const float4*)a1s)[lane];
        float4 Bv = ((const float4*)a2s)[lane];
        float4 wv[8];
#pragma unroll
        for (int c = 0; c < 2; ++c) {
#pragma unroll
            for (int j = 0; j < 8; ++j) {
                int d = wave + 16 * (c * 8 + j);
                wv[j] = ((const float4*)(W + (size_t)d * F_DIM))[lane];
            }
#pragma unroll
            for (int j = 0; j < 8; ++j) {
                int d = wave + 16 * (c * 8 + j);
                float p = dot4(wv[j], A), q = dot4(wv[j], Bv);
                for (int off = 32; off > 0; off >>= 1) {
                    p += __shfl_down(p, off);
                    q += __shfl_down(q, off);
                }
                if (lane == 0) { su[d] = p; sv[d] = q; }
            }
        }
    }
    __syncthreads();

    // p,q for this b (redundant per w): wave handles t = wave + 16*k; 8-deep prefetch
    {
        float4 uu = ((const float4*)su)[lane];
        float4 vv = ((const float4*)sv)[lane];
        float4 xv[8];
#pragma unroll
        for (int c = 0; c < 4; ++c) {
#pragma unroll
            for (int j = 0; j < 8; ++j) {
                int t = wave + 16 * (c * 8 + j);
                if (t <= tn)               // wave-uniform
                    xv[j] = ((const float4*)x)[((size_t)t * B_DIM + b) * (D_DIM / 4) + lane];
            }
#pragma unroll
            for (int j = 0; j < 8; ++j) {
                int t = wave + 16 * (c * 8 + j);
                if (t <= tn) {
                    float pp = dot4(xv[j], uu), qq = dot4(xv[j], vv);
                    for (int off = 32; off > 0; off >>= 1) {
                        pp += __shfl_down(pp, off);
                        qq += __shfl_down(qq, off);
                    }
                    if (lane == 0) { sp[t] = pp; sq[t] = qq; }
                }
            }
        }
    }
    __syncthreads();

    float scale = L2E / (float)w;
    // f2L (log2 domain) + M
    if (tid < 512) {
        int j = tid;
        float v = NEGL;
        if (j < cnt) {                     // j+w-1 <= tn: sq written
            float a = sq[j];
            if (w > 1) a += sq[j + 1];
            if (w > 2) a += sq[j + 2];
            v = a * scale;
        }
        f2L[j] = v;
        float m = v;
        for (int off = 32; off > 0; off >>= 1) m = fmaxf(m, __shfl_down(m, off));
        if (lane == 0) red[wave] = m;
        if (j < cnt) {
            float a = sp[j];
            if (w > 1) a += sp[j + 1];
            if (w > 2) a += sp[j + 2];
            fx[j] = a * scale;
        }
    }
    __syncthreads();
    float M = red[0];
#pragma unroll
    for (int k = 1; k < 8; ++k) M = fmaxf(M, red[k]);

    // row pass: thread = (i = tid&511, jh = tid>>9); inner j over half-range
    {
        int i = tid & 511, jh = tid >> 9;
        float r = 0.f;
        if (i < cnt) {
            float f1 = fx[i];
            float s0 = f1 + M;
            float mrow = fmaxf(s0, ALPHA * s0);   // analytic row max (lrelu monotone)
            int j0 = jh * 256, j1 = min(j0 + 256, cnt);
            for (int j = j0; j < j1; ++j) {
                float s = f1 + f2L[j];
                s = fmaxf(s, ALPHA * s);
                r += __builtin_amdgcn_exp2f(s - mrow);
            }
        }
        part[jh][i] = r;
    }
    __syncthreads();
    if (tid < 512 && tid < cnt) {
        float s0 = fx[tid] + M;
        float mrow = fmaxf(s0, ALPHA * s0);
        fy[tid] = mrow + __builtin_amdgcn_logf(part[0][tid] + part[1][tid]);  // log2
    }
    __syncthreads();

    // col pass: thread = (j = tid&511, ih = tid>>9); inner i over half-range
    {
        int j = tid & 511, ih = tid >> 9;
        float acc = 0.f;
        if (j < cnt) {
            float f2j = f2L[j];
            int i0 = ih * 256, i1 = min(i0 + 256, cnt);
            for (int i = i0; i < i1; ++i) {
                float s = fx[i] + f2j;
                s = fmaxf(s, ALPHA * s);
                acc += __builtin_amdgcn_exp2f(s - fy[i]);
            }
        }
        part[ih][j] = acc;                 // safe: prior use consumed pre-sync
    }
    __syncthreads();
    if (tid < 512) {
        int j = tid;
        GG[j] = (j < cnt) ? (part[0][j] + part[1][j]) / (float)cnt : 0.f;
    }
}

// ---------- Node 2: fused Z + GEMV -> atomicAdd out (proven body) ----------
// 256 blocks (64 b x 4 chunks of 128 t) x 512 threads.
__global__ __launch_bounds__(512) void g_zout(const float* __restrict__ x,
                                              const int* __restrict__ turns,
                                              const float* __restrict__ W,
                                              const float* __restrict__ ws,
                                              float* __restrict__ out) {
    int b = blockIdx.x >> 2;
    int chunk = blockIdx.x & 3;
    int tn = turns[b];
    int t0 = chunk * 128;
    if (t0 > tn) return;                   // zero contribution (block-uniform)
    int tid = threadIdx.x;
    __shared__ float Cs[128];
    __shared__ float4 zp[512];
    __shared__ float Zs[D_DIM];
    __shared__ float ored[512];
    if (tid < 128) {
        int t = t0 + tid;
        const float* G1 = ws + GG_OFF + (0 * B_DIM + b) * T_DIM;
        const float* G2 = ws + GG_OFF + (1 * B_DIM + b) * T_DIM;
        const float* G3 = ws + GG_OFF + (2 * B_DIM + b) * T_DIM;
        // GG is zero beyond each window's cnt -> C[t]=0 for t>tn automatically.
        float g2 = G2[t] + (t >= 1 ? G2[t - 1] : 0.f);
        float g3 = G3[t] + (t >= 1 ? G3[t - 1] : 0.f) + (t >= 2 ? G3[t - 2] : 0.f);
        float vws = 1.f + (tn >= 1 ? 1.f : 0.f) + (tn >= 2 ? 1.f : 0.f);
        Cs[tid] = (G1[t] + 0.5f * g2 + (1.0f / 3.0f) * g3) / vws;
    }
    __syncthreads();
    int wave = tid >> 6, lane = tid & 63;
    float4 z = make_float4(0.f, 0.f, 0.f, 0.f);
    {
        size_t base = ((size_t)(t0 + wave * 16) * B_DIM + b) * (D_DIM / 4) + lane;
#pragma unroll 8
        for (int tt = 0; tt < 16; ++tt) {
            float c = Cs[wave * 16 + tt];
            float4 xv = ((const float4*)x)[base + (size_t)tt * (B_DIM * D_DIM / 4)];
            z.x += c * xv.x; z.y += c * xv.y; z.z += c * xv.z; z.w += c * xv.w;
        }
    }
    zp[tid] = z;
    __syncthreads();
    if (tid < 64) {
        float4 a = zp[tid];
#pragma unroll
        for (int k = 1; k < 8; ++k) {
            float4 bb = zp[k * 64 + tid];
            a.x += bb.x; a.y += bb.y; a.z += bb.z; a.w += bb.w;
        }
        ((float4*)Zs)[tid] = a;
    }
    __syncthreads();
    int f = tid & 255, dh = tid >> 8;
    float acc = 0.f;
#pragma unroll 8
    for (int dd = dh * 128; dd < dh * 128 + 128; ++dd)
        acc += Zs[dd] * W[(size_t)dd * F_DIM + f];
    ored[tid] = acc;
    __syncthreads();
    if (tid < 256)
        atomicAdd(&out[b * F_DIM + tid], ored[tid] + ored[tid + 256]);
}

extern "C" void kernel_launch(void* const* d_in, const int* in_sizes, int n_in,
                              void* d_out, int out_size, void* d_ws, size_t ws_size,
                              hipStream_t stream) {
    const float* x = (const float*)d_in[0];     // (T,B,D) fp32
    const int* turns = (const int*)d_in[1];     // (B,) int32
    const float* W = (const float*)d_in[2];     // (D,F)
    const float* a1 = (const float*)d_in[3];    // (F,)
    const float* a2 = (const float*)d_in[4];    // (F,)
    float* out = (float*)d_out;                 // (B,F)
    float* ws = (float*)d_ws;

    g_attn_all<<<B_DIM * 3, 1024, 0, stream>>>(x, turns, W, a1, a2, ws, out);
    g_zout<<<B_DIM * 4, 512, 0, stream>>>(x, turns, W, ws, out);
}

// Round 11
// 51.205 us; speedup vs baseline: 1.5566x; 1.5303x over previous
//
#include <hip/hip_runtime.h>
#include <math.h>

#define T_DIM 512
#define B_DIM 64
#define D_DIM 256
#define F_DIM 256
#define ALPHA 0.2f
#define L2E 1.44269504089f
#define NEGL -1.0e38f

// workspace layout (floats). Every slot consumed is written the same call.
#define U_OFF 0
#define V_OFF 256
#define P_OFF 512
#define Q_OFF (P_OFF + B_DIM * T_DIM)
#define GG_OFF (Q_OFF + B_DIM * T_DIM)             // gg[3][B][T]

__device__ __forceinline__ float dot4(float4 a, float4 b) {
    return a.x * b.x + a.y * b.y + a.z * b.z + a.w * b.w;
}

// ---------- Node 1: u = W@a1, v = W@a2. 64 blocks x 256 thr ----------
__global__ __launch_bounds__(256) void g_uv(const float* __restrict__ W,
                                            const float* __restrict__ a1,
                                            const float* __restrict__ a2,
                                            float* __restrict__ ws) {
    int tid = threadIdx.x;
    int wave = tid >> 6, lane = tid & 63;
    int d = blockIdx.x * 4 + wave;
    float4 wv = ((const float4*)(W + (size_t)d * F_DIM))[lane];
    float4 a1v = ((const float4*)a1)[lane];
    float4 a2v = ((const float4*)a2)[lane];
    float p = dot4(wv, a1v), q = dot4(wv, a2v);
    for (int off = 32; off > 0; off >>= 1) {
        p += __shfl_down(p, off);
        q += __shfl_down(q, off);
    }
    if (lane == 0) {
        ws[U_OFF + d] = p;
        ws[V_OFF + d] = q;
    }
}

// ---------- Node 2: p,q dot products. 512 blocks x 512 thr ----------
// Clamp-trick: loads are UNCONDITIONAL (row min(t,tn)) so the compiler keeps
// all 8 in flight; only reduce/store is guarded (wave-uniform).
__global__ __launch_bounds__(512) void g_pq(const float* __restrict__ x,
                                            const int* __restrict__ turns,
                                            float* __restrict__ ws) {
    __shared__ float su[D_DIM], sv[D_DIM];
    int tid = threadIdx.x;
    if (tid < 64) ((float4*)su)[tid] = ((const float4*)(ws + U_OFF))[tid];
    else if (tid < 128) ((float4*)sv)[tid - 64] = ((const float4*)(ws + V_OFF))[tid - 64];
    __syncthreads();
    int lane = tid & 63;
    int gw = blockIdx.x * 8 + (tid >> 6);  // [0, 4096)
    int b = gw & 63;
    int tbase = gw >> 6;                   // [0, 64)
    int tn = turns[b];
    float4 uv = ((const float4*)su)[lane];
    float4 vv = ((const float4*)sv)[lane];
    float4 xv[8];
#pragma unroll
    for (int k = 0; k < 8; ++k) {
        int t = min(tbase + k * 64, tn);   // always valid address
        xv[k] = ((const float4*)x)[((size_t)t * B_DIM + b) * (D_DIM / 4) + lane];
    }
#pragma unroll
    for (int k = 0; k < 8; ++k) {
        int t = tbase + k * 64;
        if (t <= tn) {                     // wave-uniform
            float pp = dot4(xv[k], uv), qq = dot4(xv[k], vv);
            for (int off = 32; off > 0; off >>= 1) {
                pp += __shfl_down(pp, off);
                qq += __shfl_down(qq, off);
            }
            if (lane == 0) {
                ws[P_OFF + b * T_DIM + t] = pp;
                ws[Q_OFF + b * T_DIM + t] = qq;
            }
        }
    }
}

// ---------- Node 3: fused attention row+col per (b,w). 192 blocks x 1024 thr ----------
// float4 LDS reads in both O(cnt^2) passes; padded arrays (exp2 underflow -> 0)
// remove all tails. Blocks 0..31 zero d_out for Node 4 atomics.
__global__ __launch_bounds__(1024) void g_attn(const int* __restrict__ turns,
                                               float* __restrict__ ws,
                                               float* __restrict__ out) {
    int bi = blockIdx.x, tid = threadIdx.x;
    if (bi < 32 && tid < 512) out[bi * 512 + tid] = 0.f;
    int b = bi / 3, w = bi % 3 + 1;
    int tn = turns[b];
    int cnt = tn - w + 2;
    if (cnt > T_DIM) cnt = T_DIM;
    float* GG = ws + GG_OFF + ((w - 1) * B_DIM + b) * T_DIM;
    if (cnt <= 0) {                        // block-uniform, before any sync
        if (tid < 512) GG[tid] = 0.f;
        return;
    }
    __shared__ float sp[T_DIM], sq[T_DIM];
    __shared__ float f2L[T_DIM], fx[T_DIM];
    __shared__ float2 fc[T_DIM];
    __shared__ float part[2][T_DIM];
    __shared__ float red[8];

    if (tid < 128) ((float4*)sp)[tid] = ((const float4*)(ws + P_OFF + b * T_DIM))[tid];
    else if (tid < 256) ((float4*)sq)[tid - 128] = ((const float4*)(ws + Q_OFF + b * T_DIM))[tid - 128];
    __syncthreads();

    float scale = L2E / (float)w;
    int wave = tid >> 6, lane = tid & 63;
    if (tid < 512) {
        int j = tid;
        float v = NEGL;
        if (j < cnt) {                     // j+w-1 <= tn: valid
            float a = sq[j];
            if (w > 1) a += sq[j + 1];
            if (w > 2) a += sq[j + 2];
            v = a * scale;
        }
        f2L[j] = v;                        // padded with NEGL beyond cnt
        float m = v;
        for (int off = 32; off > 0; off >>= 1) m = fmaxf(m, __shfl_down(m, off));
        if (lane == 0) red[wave] = m;
        float f1 = 0.f;
        if (j < cnt) {
            float a = sp[j];
            if (w > 1) a += sp[j + 1];
            if (w > 2) a += sp[j + 2];
            f1 = a * scale;
        }
        fx[j] = f1;
    }
    __syncthreads();
    float M = red[0];
#pragma unroll
    for (int k = 1; k < 8; ++k) M = fmaxf(M, red[k]);

    // row pass: i = tid&511, half jh = tid>>9; float4 over f2L
    {
        int i = tid & 511, jh = tid >> 9;
        float r = 0.f;
        if (i < cnt) {
            float f1 = fx[i];
            float s0 = f1 + M;
            float mrow = fmaxf(s0, ALPHA * s0);   // analytic row max (lrelu monotone)
            int j0 = jh * 256;
            int j1 = min(j0 + 256, cnt);
            int n4 = (j1 - j0 + 3) >> 2;          // padded: safe to round up
            const float4* f2v = (const float4*)(f2L + j0);
            for (int k = 0; k < n4; ++k) {
                float4 f = f2v[k];
                float s0a = f1 + f.x, s0b = f1 + f.y, s0c = f1 + f.z, s0d = f1 + f.w;
                s0a = fmaxf(s0a, ALPHA * s0a); s0b = fmaxf(s0b, ALPHA * s0b);
                s0c = fmaxf(s0c, ALPHA * s0c); s0d = fmaxf(s0d, ALPHA * s0d);
                r += __builtin_amdgcn_exp2f(s0a - mrow) + __builtin_amdgcn_exp2f(s0b - mrow)
                   + __builtin_amdgcn_exp2f(s0c - mrow) + __builtin_amdgcn_exp2f(s0d - mrow);
            }
        }
        part[jh][i] = r;
    }
    __syncthreads();
    if (tid < 512) {
        int i = tid;
        float2 v = make_float2(0.f, 3.0e38f);     // pad: exp2(s - 3e38) = 0
        if (i < cnt) {
            float s0 = fx[i] + M;
            float mrow = fmaxf(s0, ALPHA * s0);
            v = make_float2(fx[i], mrow + __builtin_amdgcn_logf(part[0][i] + part[1][i]));
        }
        fc[i] = v;
    }
    __syncthreads();

    // col pass: j = tid&511, half ih = tid>>9; float4 over fc (2 pairs per read)
    {
        int j = tid & 511, ih = tid >> 9;
        float acc = 0.f;
        if (j < cnt) {
            float f2j = f2L[j];
            int i0 = ih * 256;
            int i1 = min(i0 + 256, cnt);
            int n2 = (i1 - i0 + 1) >> 1;          // padded fc: safe to round up
            const float4* fcv = (const float4*)(fc + i0);
            for (int k = 0; k < n2; ++k) {
                float4 f = fcv[k];                // (f1_i, ci_i, f1_i+1, ci_i+1)
                float sa = f.x + f2j, sb = f.z + f2j;
                sa = fmaxf(sa, ALPHA * sa); sb = fmaxf(sb, ALPHA * sb);
                acc += __builtin_amdgcn_exp2f(sa - f.y) + __builtin_amdgcn_exp2f(sb - f.w);
            }
        }
        part[ih][j] = acc;
    }
    __syncthreads();
    if (tid < 512) {
        int j = tid;
        GG[j] = (j < cnt) ? (part[0][j] + part[1][j]) / (float)cnt : 0.f;
    }
}

// ---------- Node 4: fused Z + GEMV -> atomicAdd out (proven body) ----------
// 256 blocks (64 b x 4 chunks of 128 t) x 512 threads.
__global__ __launch_bounds__(512) void g_zout(const float* __restrict__ x,
                                              const int* __restrict__ turns,
                                              const float* __restrict__ W,
                                              const float* __restrict__ ws,
                                              float* __restrict__ out) {
    int b = blockIdx.x >> 2;
    int chunk = blockIdx.x & 3;
    int tn = turns[b];
    int t0 = chunk * 128;
    if (t0 > tn) return;                   // zero contribution (block-uniform)
    int tid = threadIdx.x;
    __shared__ float Cs[128];
    __shared__ float4 zp[512];
    __shared__ float Zs[D_DIM];
    __shared__ float ored[512];
    if (tid < 128) {
        int t = t0 + tid;
        const float* G1 = ws + GG_OFF + (0 * B_DIM + b) * T_DIM;
        const float* G2 = ws + GG_OFF + (1 * B_DIM + b) * T_DIM;
        const float* G3 = ws + GG_OFF + (2 * B_DIM + b) * T_DIM;
        float g2 = G2[t] + (t >= 1 ? G2[t - 1] : 0.f);
        float g3 = G3[t] + (t >= 1 ? G3[t - 1] : 0.f) + (t >= 2 ? G3[t - 2] : 0.f);
        float vws = 1.f + (tn >= 1 ? 1.f : 0.f) + (tn >= 2 ? 1.f : 0.f);
        Cs[tid] = (G1[t] + 0.5f * g2 + (1.0f / 3.0f) * g3) / vws;
    }
    __syncthreads();
    int wave = tid >> 6, lane = tid & 63;
    float4 z = make_float4(0.f, 0.f, 0.f, 0.f);
    {
        size_t base = ((size_t)(t0 + wave * 16) * B_DIM + b) * (D_DIM / 4) + lane;
#pragma unroll 8
        for (int tt = 0; tt < 16; ++tt) {
            float c = Cs[wave * 16 + tt];
            float4 xv = ((const float4*)x)[base + (size_t)tt * (B_DIM * D_DIM / 4)];
            z.x += c * xv.x; z.y += c * xv.y; z.z += c * xv.z; z.w += c * xv.w;
        }
    }
    zp[tid] = z;
    __syncthreads();
    if (tid < 64) {
        float4 a = zp[tid];
#pragma unroll
        for (int k = 1; k < 8; ++k) {
            float4 bb = zp[k * 64 + tid];
            a.x += bb.x; a.y += bb.y; a.z += bb.z; a.w += bb.w;
        }
        ((float4*)Zs)[tid] = a;
    }
    __syncthreads();
    int f = tid & 255, dh = tid >> 8;
    float acc = 0.f;
#pragma unroll 8
    for (int dd = dh * 128; dd < dh * 128 + 128; ++dd)
        acc += Zs[dd] * W[(size_t)dd * F_DIM + f];
    ored[tid] = acc;
    __syncthreads();
    if (tid < 256)
        atomicAdd(&out[b * F_DIM + tid], ored[tid] + ored[tid + 256]);
}

extern "C" void kernel_launch(void* const* d_in, const int* in_sizes, int n_in,
                              void* d_out, int out_size, void* d_ws, size_t ws_size,
                              hipStream_t stream) {
    const float* x = (const float*)d_in[0];     // (T,B,D) fp32
    const int* turns = (const int*)d_in[1];     // (B,) int32
    const float* W = (const float*)d_in[2];     // (D,F)
    const float* a1 = (const float*)d_in[3];    // (F,)
    const float* a2 = (const float*)d_in[4];    // (F,)
    float* out = (float*)d_out;                 // (B,F)
    float* ws = (float*)d_ws;

    g_uv<<<B_DIM, 256, 0, stream>>>(W, a1, a2, ws);
    g_pq<<<512, 512, 0, stream>>>(x, turns, ws);
    g_attn<<<B_DIM * 3, 1024, 0, stream>>>(turns, ws, out);
    g_zout<<<B_DIM * 4, 512, 0, stream>>>(x, turns, W, ws, out);
}

// Round 13
// 46.828 us; speedup vs baseline: 1.7021x; 1.0935x over previous
//
#include <hip/hip_runtime.h>
#include <math.h>

#define T_DIM 512
#define B_DIM 64
#define D_DIM 256
#define F_DIM 256
#define ALPHA 0.2f
#define L2E 1.44269504089f
#define NEGL -1.0e38f

// workspace layout (floats). Every slot consumed is written the same call.
#define U_OFF 0
#define V_OFF 256
#define P_OFF 512
#define Q_OFF (P_OFF + B_DIM * T_DIM)
#define FC_OFF (Q_OFF + B_DIM * T_DIM)    // float2 fc[3][B][T] = (f1_i, ci_i)

__device__ __forceinline__ float dot4(float4 a, float4 b) {
    return a.x * b.x + a.y * b.y + a.z * b.z + a.w * b.w;
}

// Wave64 sum via DPP butterfly (VALU-rate, no LDS pipe). Result in lane 63.
__device__ __forceinline__ float dpp_sum(float x) {
    union { float f; int i; } a, t;
    a.f = x;
    t.i = __builtin_amdgcn_update_dpp(0, a.i, 0x111, 0xf, 0xf, true); a.f += t.f; // row_shr:1
    t.i = __builtin_amdgcn_update_dpp(0, a.i, 0x112, 0xf, 0xf, true); a.f += t.f; // row_shr:2
    t.i = __builtin_amdgcn_update_dpp(0, a.i, 0x114, 0xf, 0xf, true); a.f += t.f; // row_shr:4
    t.i = __builtin_amdgcn_update_dpp(0, a.i, 0x118, 0xf, 0xf, true); a.f += t.f; // row_shr:8
    t.i = __builtin_amdgcn_update_dpp(0, a.i, 0x142, 0xf, 0xf, true); a.f += t.f; // row_bcast:15
    t.i = __builtin_amdgcn_update_dpp(0, a.i, 0x143, 0xf, 0xf, true); a.f += t.f; // row_bcast:31
    return a.f;  // lane 63 holds the wave sum
}

// ---------- Node 1: u = W@a1, v = W@a2; zero d_out. 64 blocks x 256 thr ----------
__global__ __launch_bounds__(256) void g_uv(const float* __restrict__ W,
                                            const float* __restrict__ a1,
                                            const float* __restrict__ a2,
                                            float* __restrict__ ws,
                                            float* __restrict__ out) {
    int tid = threadIdx.x;
    out[blockIdx.x * 256 + tid] = 0.f;     // zero d_out for Node 4 atomics
    int wave = tid >> 6, lane = tid & 63;
    int d = blockIdx.x * 4 + wave;
    float4 wv = ((const float4*)(W + (size_t)d * F_DIM))[lane];
    float4 a1v = ((const float4*)a1)[lane];
    float4 a2v = ((const float4*)a2)[lane];
    float p = dpp_sum(dot4(wv, a1v));
    float q = dpp_sum(dot4(wv, a2v));
    if (lane == 63) {
        ws[U_OFF + d] = p;
        ws[V_OFF + d] = q;
    }
}

// ---------- Node 2: p,q dot products. 512 blocks x 512 thr ----------
// Clamp-trick unconditional loads (8 in flight) + DPP reduction (no ds_bpermute).
__global__ __launch_bounds__(512) void g_pq(const float* __restrict__ x,
                                            const int* __restrict__ turns,
                                            float* __restrict__ ws) {
    __shared__ float su[D_DIM], sv[D_DIM];
    int tid = threadIdx.x;
    if (tid < 64) ((float4*)su)[tid] = ((const float4*)(ws + U_OFF))[tid];
    else if (tid < 128) ((float4*)sv)[tid - 64] = ((const float4*)(ws + V_OFF))[tid - 64];
    __syncthreads();
    int lane = tid & 63;
    int gw = blockIdx.x * 8 + (tid >> 6);  // [0, 4096)
    int b = gw & 63;
    int tbase = gw >> 6;                   // [0, 64)
    int tn = turns[b];
    float4 uv = ((const float4*)su)[lane];
    float4 vv = ((const float4*)sv)[lane];
    float4 xv[8];
#pragma unroll
    for (int k = 0; k < 8; ++k) {
        int t = min(tbase + k * 64, tn);   // always valid address
        xv[k] = ((const float4*)x)[((size_t)t * B_DIM + b) * (D_DIM / 4) + lane];
    }
#pragma unroll
    for (int k = 0; k < 8; ++k) {
        int t = tbase + k * 64;
        if (t <= tn) {                     // wave-uniform
            float pp = dpp_sum(dot4(xv[k], uv));
            float qq = dpp_sum(dot4(xv[k], vv));
            if (lane == 63) {
                ws[P_OFF + b * T_DIM + t] = pp;
                ws[Q_OFF + b * T_DIM + t] = qq;
            }
        }
    }
}

// ---------- Node 3: balanced row pass, no atomics. 768 blocks (b,w,ic) x 1024 ----------
// Each block: full-j row sums for its 128 i's -> fc[(w-1)][b][i] = (f1_i, ci_i).
// Pads (i >= cnt) written as (0, 3e38) so downstream float4 loops need no tails.
__global__ __launch_bounds__(1024) void g_row(const int* __restrict__ turns,
                                              float* __restrict__ ws) {
    int bi = blockIdx.x, tid = threadIdx.x;
    int b = bi / 12, rem = bi % 12;
    int w = (rem >> 2) + 1, ic = rem & 3;
    int tn = turns[b];
    int cnt = tn - w + 2;
    if (cnt > T_DIM) cnt = T_DIM;
    float2* FC = (float2*)(ws + FC_OFF) + ((w - 1) * B_DIM + b) * T_DIM;
    if (cnt <= 0) return;                  // block-uniform; fc never read for this w
    __shared__ float sp[T_DIM], sq[T_DIM], f2L[T_DIM];
    __shared__ float part[8][128];
    __shared__ float redm[8];
    if (tid < 128) ((float4*)sp)[tid] = ((const float4*)(ws + P_OFF + b * T_DIM))[tid];
    else if (tid < 256) ((float4*)sq)[tid - 128] = ((const float4*)(ws + Q_OFF + b * T_DIM))[tid - 128];
    __syncthreads();
    float scale = L2E / (float)w;
    int wave = tid >> 6, lane = tid & 63;
    if (tid < 512) {
        int j = tid;
        float v = NEGL;
        if (j < cnt) {                     // j+w-1 <= tn: valid
            float a = sq[j];
            if (w > 1) a += sq[j + 1];
            if (w > 2) a += sq[j + 2];
            v = a * scale;
        }
        f2L[j] = v;                        // padded NEGL beyond cnt
        float m = v;
        for (int off = 32; off > 0; off >>= 1) m = fmaxf(m, __shfl_down(m, off));
        if (lane == 0) redm[wave] = m;
    }
    __syncthreads();
    float M = redm[0];
#pragma unroll
    for (int k = 1; k < 8; ++k) M = fmaxf(M, redm[k]);

    int il = tid & 127, oct = tid >> 7;
    int i = ic * 128 + il;
    float r = 0.f;
    if (i < cnt) {
        float a = sp[i];
        if (w > 1) a += sp[i + 1];
        if (w > 2) a += sp[i + 2];
        float f1 = a * scale;
        float s0 = f1 + M;
        float mrow = fmaxf(s0, ALPHA * s0);   // analytic row max (lrelu monotone)
        const float4* fv = (const float4*)(f2L + oct * 64);
#pragma unroll 4
        for (int k = 0; k < 16; ++k) {        // 64 j's per octant, pad-safe
            float4 f = fv[k];
            float sa = f1 + f.x, sb = f1 + f.y, sc = f1 + f.z, sd = f1 + f.w;
            sa = fmaxf(sa, ALPHA * sa); sb = fmaxf(sb, ALPHA * sb);
            sc = fmaxf(sc, ALPHA * sc); sd = fmaxf(sd, ALPHA * sd);
            r += __builtin_amdgcn_exp2f(sa - mrow) + __builtin_amdgcn_exp2f(sb - mrow)
               + __builtin_amdgcn_exp2f(sc - mrow) + __builtin_amdgcn_exp2f(sd - mrow);
        }
    }
    part[oct][il] = r;
    __syncthreads();
    if (tid < 128) {
        int i2 = ic * 128 + tid;
        float2 pr = make_float2(0.f, 3.0e38f);   // pad: exp2(s - 3e38) = 0
        if (i2 < cnt) {
            float rt = part[0][tid];
#pragma unroll
            for (int k = 1; k < 8; ++k) rt += part[k][tid];
            float a = sp[i2];
            if (w > 1) a += sp[i2 + 1];
            if (w > 2) a += sp[i2 + 2];
            float f1 = a * scale;
            float s0 = f1 + M;
            float mrow = fmaxf(s0, ALPHA * s0);
            pr = make_float2(f1, mrow + __builtin_amdgcn_logf(rt));   // log2 domain
        }
        FC[i2] = pr;
    }
}

// ---------- Node 4: col pass + Z + GEMV -> atomicAdd out. 256 blocks x 512 ----------
__global__ __launch_bounds__(512) void g_colzout(const float* __restrict__ x,
                                                 const int* __restrict__ turns,
                                                 const float* __restrict__ W,
                                                 const float* __restrict__ ws,
                                                 float* __restrict__ out) {
    int b = blockIdx.x >> 2, chunk = blockIdx.x & 3;
    int tn = turns[b];
    int t0 = chunk * 128;
    if (t0 > tn) return;                   // C=0 there; out zeroed in Node 1
    int tid = threadIdx.x;
    __shared__ float sq[T_DIM];
    __shared__ float4 fcs4[3][T_DIM / 2];  // fc pairs, float4 = 2 (f1,ci) pairs
    __shared__ float Gs[3][132];
    __shared__ float partq[128][4];
    __shared__ float part2[2][128];
    __shared__ float Cs[128];
    __shared__ float4 zp[512];
    __shared__ float Zs[D_DIM];
    __shared__ float ored[512];

    if (tid < 128) ((float4*)sq)[tid] = ((const float4*)(ws + Q_OFF + b * T_DIM))[tid];
    for (int k = tid; k < 3 * 256; k += 512) {
        int wi = k >> 8, kk = k & 255;
        fcs4[wi][kk] = ((const float4*)(ws + FC_OFF))[(wi * B_DIM + b) * 256 + kk];
    }
    __syncthreads();

    for (int w = 1; w <= 3; ++w) {
        int cw = tn - w + 2;
        if (cw > T_DIM) cw = T_DIM;
        bool act = cw > 0;                 // block-uniform
        float scale = L2E / (float)w;
        if (act) {
            // phase I: j = t0 + (tid>>2), i-quarter iq = tid&3 (64 float4 = 128 i)
            {
                int jj = tid >> 2, iq = tid & 3;
                int j = t0 + jj;
                float acc = 0.f;
                if (j < cw) {
                    float a = sq[j];
                    if (w > 1) a += sq[j + 1];
                    if (w > 2) a += sq[j + 2];
                    float f2j = a * scale;
                    const float4* fv = fcs4[w - 1] + iq * 64;
                    for (int k = 0; k < 64; ++k) {       // pad-safe
                        float4 f = fv[k];
                        float sa = f.x + f2j, sb = f.z + f2j;
                        sa = fmaxf(sa, ALPHA * sa); sb = fmaxf(sb, ALPHA * sb);
                        acc += __builtin_amdgcn_exp2f(sa - f.y)
                             + __builtin_amdgcn_exp2f(sb - f.w);
                    }
                }
                partq[jj][iq] = acc;
            }
            // phase II: j = t0-2, t0-1; 128-way i-split (2 float4 = 4 i each)
            if (tid < 256) {
                int e = tid >> 7, q2 = tid & 127;
                int j2 = t0 - 2 + e;
                float acc = 0.f;
                if (j2 >= 0 && j2 < cw) {
                    float a = sq[j2];
                    if (w > 1) a += sq[j2 + 1];
                    if (w > 2) a += sq[j2 + 2];
                    float f2j = a * scale;
                    const float4* fv = fcs4[w - 1] + q2 * 2;
#pragma unroll
                    for (int k = 0; k < 2; ++k) {
                        float4 f = fv[k];
                        float sa = f.x + f2j, sb = f.z + f2j;
                        sa = fmaxf(sa, ALPHA * sa); sb = fmaxf(sb, ALPHA * sb);
                        acc += __builtin_amdgcn_exp2f(sa - f.y)
                             + __builtin_amdgcn_exp2f(sb - f.w);
                    }
                }
                part2[e][q2] = acc;
            }
        }
        __syncthreads();
        if (act) {
            float invc = 1.0f / (float)cw;
            if (tid < 128) {
                int j = t0 + tid;
                float s = partq[tid][0] + partq[tid][1] + partq[tid][2] + partq[tid][3];
                Gs[w - 1][2 + tid] = (j < cw) ? s * invc : 0.f;
            } else if (tid < 130) {
                int e = tid - 128;
                int j2 = t0 - 2 + e;
                float s = 0.f;
                for (int k = 0; k < 128; ++k) s += part2[e][k];
                Gs[w - 1][e] = (j2 >= 0 && j2 < cw) ? s * invc : 0.f;
            }
        } else if (tid < 132) {
            Gs[w - 1][tid] = 0.f;
        }
        __syncthreads();
    }

    // C[t] with vws folded
    if (tid < 128) {
        float g1 = Gs[0][2 + tid];
        float g2 = Gs[1][2 + tid] + Gs[1][1 + tid];
        float g3 = Gs[2][2 + tid] + Gs[2][1 + tid] + Gs[2][tid];
        float vws = 1.f + (tn >= 1 ? 1.f : 0.f) + (tn >= 2 ? 1.f : 0.f);
        Cs[tid] = (g1 + 0.5f * g2 + (1.0f / 3.0f) * g3) / vws;
    }
    __syncthreads();

    // Z accumulate over this t-chunk (proven body)
    int wave = tid >> 6, lane = tid & 63;
    float4 z = make_float4(0.f, 0.f, 0.f, 0.f);
    {
        size_t base = ((size_t)(t0 + wave * 16) * B_DIM + b) * (D_DIM / 4) + lane;
#pragma unroll 8
        for (int tt = 0; tt < 16; ++tt) {
            float c = Cs[wave * 16 + tt];
            float4 xv = ((const float4*)x)[base + (size_t)tt * (B_DIM * D_DIM / 4)];
            z.x += c * xv.x; z.y += c * xv.y; z.z += c * xv.z; z.w += c * xv.w;
        }
    }
    zp[tid] = z;
    __syncthreads();
    if (tid < 64) {
        float4 a = zp[tid];
#pragma unroll
        for (int k = 1; k < 8; ++k) {
            float4 bb = zp[k * 64 + tid];
            a.x += bb.x; a.y += bb.y; a.z += bb.z; a.w += bb.w;
        }
        ((float4*)Zs)[tid] = a;
    }
    __syncthreads();
    int f = tid & 255, dh = tid >> 8;
    float acc = 0.f;
#pragma unroll 8
    for (int dd = dh * 128; dd < dh * 128 + 128; ++dd)
        acc += Zs[dd] * W[(size_t)dd * F_DIM + f];
    ored[tid] = acc;
    __syncthreads();
    if (tid < 256)
        atomicAdd(&out[b * F_DIM + tid], ored[tid] + ored[tid + 256]);
}

extern "C" void kernel_launch(void* const* d_in, const int* in_sizes, int n_in,
                              void* d_out, int out_size, void* d_ws, size_t ws_size,
                              hipStream_t stream) {
    const float* x = (const float*)d_in[0];     // (T,B,D) fp32
    const int* turns = (const int*)d_in[1];     // (B,) int32
    const float* W = (const float*)d_in[2];     // (D,F)
    const float* a1 = (const float*)d_in[3];    // (F,)
    const float* a2 = (const float*)d_in[4];    // (F,)
    float* out = (float*)d_out;                 // (B,F)
    float* ws = (float*)d_ws;

    g_uv<<<B_DIM, 256, 0, stream>>>(W, a1, a2, ws, out);
    g_pq<<<512, 512, 0, stream>>>(x, turns, ws);
    g_row<<<B_DIM * 12, 1024, 0, stream>>>(turns, ws);
    g_colzout<<<B_DIM * 4, 512, 0, stream>>>(x, turns, W, ws, out);
}